// Round 3
// baseline (1984.763 us; speedup 1.0000x reference)
//
#include <hip/hip_runtime.h>
#include <math.h>

#define NB   2
#define SEQ  2048
#define NHD  16
#define HDD  64
#define HID  1024
#define TOPK 128

// ---------------- fast fp64 exp(s): branchless, |s| <= ~40, rel err ~7e-12 --------------------------
__device__ inline double fast_exp(double s) {
  const double LOG2E = 1.4426950408889634073599246810019;
  double t = s * LOG2E;
  double n = __builtin_rint(t);
  double f = t - n;                                   // |f| <= 0.5
  double r = f * 0.69314718055994530941723212145818;  // ln2
  double p = 2.7557319223985890652557319223986e-6;    // 1/9!
  p = fma(p, r, 2.4801587301587301587301587301587e-5);
  p = fma(p, r, 1.9841269841269841269841269841270e-4);
  p = fma(p, r, 1.3888888888888888888888888888889e-3);
  p = fma(p, r, 8.3333333333333333333333333333333e-3);
  p = fma(p, r, 4.1666666666666666666666666666667e-2);
  p = fma(p, r, 1.6666666666666666666666666666667e-1);
  p = fma(p, r, 0.5);
  p = fma(p, r, 1.0);
  p = fma(p, r, 1.0);
  int ni = (int)n;
  double sc = __longlong_as_double((long long)(1023 + ni) << 52);
  return p * sc;
}

// ---------------- K0a: vw = mean(sparse_W_V, axis=2), ow = mean(sparse_W_O, axis=1) (fp64) ----------
__global__ void k_prep_means(const float* __restrict__ sWV, const float* __restrict__ sWO,
                             double* __restrict__ vw, double* __restrict__ ow) {
  int t = threadIdx.x;
  for (int o = t; o < NHD * HDD; o += 256) {
    const float* p = sWV + (size_t)o * TOPK;
    double s = 0.0;
    for (int i = 0; i < TOPK; i++) s += (double)p[i];
    vw[o] = s * (1.0 / 128.0);
    int h = o >> 6, d = o & 63;
    const float* q = sWO + ((size_t)h * TOPK) * HDD + d;
    double s2 = 0.0;
    for (int i = 0; i < TOPK; i++) s2 += (double)q[(size_t)i * HDD];
    ow[o] = s2 * (1.0 / 128.0);
  }
}

// ---------------- K0b: WVP[(n*16+h), j] = sum_d W_V[n*64+d, j]*vw[h,d]  (fp64)
//                       G[(m*16+h), o]  = sum_d ow[h,d]*W_O[o, m*64+d]  (fp32) ----------------------
__global__ void k_prep_wvp_g(const float* __restrict__ W_V, const float* __restrict__ W_O,
                             const double* __restrict__ vw, const double* __restrict__ ow,
                             double* __restrict__ WVP, float* __restrict__ G) {
  int blk = blockIdx.x;
  int t = threadIdx.x;
  if (blk < 256) {
    int n = blk >> 4, h = blk & 15;
    for (int j = t; j < HID; j += 256) {
      double s = 0.0;
      for (int d = 0; d < 64; d++)
        s += (double)W_V[(size_t)(n * 64 + d) * HID + j] * vw[h * 64 + d];
      WVP[(size_t)blk * HID + j] = s;
    }
  } else {
    int r = blk - 256;
    int m = r >> 4, h = r & 15;
    for (int o = t; o < HID; o += 256) {
      double s = 0.0;
      for (int d = 0; d < 64; d++)
        s += ow[h * 64 + d] * (double)W_O[(size_t)o * HID + m * 64 + d];
      G[(size_t)r * HID + o] = (float)s;
    }
  }
}

// ---------------- K1: Q/K projection (fp64) + per-head LayerNorm via shfl, store fp64 ---------------
// Q is pre-scaled by 0.125 (exact power-of-two; scores become softmax-ready).
__global__ __launch_bounds__(256, 4) void k_proj_qk(
    const float* __restrict__ x, const float* __restrict__ W_Q, const float* __restrict__ W_K,
    const float* __restrict__ qw, const float* __restrict__ qb,
    const float* __restrict__ kw, const float* __restrict__ kb,
    double* __restrict__ Qh, double* __restrict__ Kh) {
  __shared__ __align__(16) double As[32][68];  // [k][row]
  __shared__ __align__(16) double Bs[32][68];

  int rt = blockIdx.x, ot = blockIdx.y;
  bool isQ = (ot < 16);
  const float* W = isQ ? W_Q : W_K;
  int head = isQ ? ot : ot - 16;
  int t = threadIdx.x;
  int tr = t >> 4, tc = t & 15;

  double acc[4][4];
  #pragma unroll
  for (int i = 0; i < 4; i++)
    #pragma unroll
    for (int j = 0; j < 4; j++) acc[i][j] = 0.0;

  for (int k0 = 0; k0 < HID; k0 += 32) {
    #pragma unroll
    for (int i = 0; i < 8; i++) {
      int idx = t + i * 256;
      int r = idx >> 5, c = idx & 31;
      As[c][r] = (double)x[(size_t)(rt * 64 + r) * HID + k0 + c];
      Bs[c][r] = (double)W[(size_t)(head * 64 + r) * HID + k0 + c];
    }
    __syncthreads();
    #pragma unroll 2
    for (int kk = 0; kk < 32; kk++) {
      double2 a01 = *(const double2*)&As[kk][tr * 4];
      double2 a23 = *(const double2*)&As[kk][tr * 4 + 2];
      double2 b01 = *(const double2*)&Bs[kk][tc * 4];
      double2 b23 = *(const double2*)&Bs[kk][tc * 4 + 2];
      acc[0][0] = fma(a01.x, b01.x, acc[0][0]);
      acc[0][1] = fma(a01.x, b01.y, acc[0][1]);
      acc[0][2] = fma(a01.x, b23.x, acc[0][2]);
      acc[0][3] = fma(a01.x, b23.y, acc[0][3]);
      acc[1][0] = fma(a01.y, b01.x, acc[1][0]);
      acc[1][1] = fma(a01.y, b01.y, acc[1][1]);
      acc[1][2] = fma(a01.y, b23.x, acc[1][2]);
      acc[1][3] = fma(a01.y, b23.y, acc[1][3]);
      acc[2][0] = fma(a23.x, b01.x, acc[2][0]);
      acc[2][1] = fma(a23.x, b01.y, acc[2][1]);
      acc[2][2] = fma(a23.x, b23.x, acc[2][2]);
      acc[2][3] = fma(a23.x, b23.y, acc[2][3]);
      acc[3][0] = fma(a23.y, b01.x, acc[3][0]);
      acc[3][1] = fma(a23.y, b01.y, acc[3][1]);
      acc[3][2] = fma(a23.y, b23.x, acc[3][2]);
      acc[3][3] = fma(a23.y, b23.y, acc[3][3]);
    }
    __syncthreads();
  }

  double lw[4], lb2[4];
  {
    const float* lwp = isQ ? qw : kw;
    const float* lbp = isQ ? qb : kb;
    #pragma unroll
    for (int j = 0; j < 4; j++) {
      lw[j]  = (double)lwp[tc * 4 + j];
      lb2[j] = (double)lbp[tc * 4 + j];
    }
  }
  double* outp = isQ ? Qh : Kh;
  double scale = isQ ? 0.125 : 1.0;  // exact
  #pragma unroll
  for (int i = 0; i < 4; i++) {
    double s = (acc[i][0] + acc[i][1]) + (acc[i][2] + acc[i][3]);
    s += __shfl_xor(s, 1); s += __shfl_xor(s, 2);
    s += __shfl_xor(s, 4); s += __shfl_xor(s, 8);
    double mu = s * (1.0 / 64.0);
    double d0 = acc[i][0] - mu, d1 = acc[i][1] - mu;
    double d2 = acc[i][2] - mu, d3 = acc[i][3] - mu;
    double v = (d0 * d0 + d1 * d1) + (d2 * d2 + d3 * d3);
    v += __shfl_xor(v, 1); v += __shfl_xor(v, 2);
    v += __shfl_xor(v, 4); v += __shfl_xor(v, 8);
    double inv = 1.0 / sqrt(v * (1.0 / 64.0) + 1e-5);
    int R = rt * 64 + tr * 4 + i;
    int b = R >> 11, ss = R & 2047;
    double* op = outp + (((size_t)b * 16 + head) * SEQ + ss) * 64 + tc * 4;
    op[0] = fma(d0 * inv, lw[0], lb2[0]) * scale;
    op[1] = fma(d1 * inv, lw[1], lb2[1]) * scale;
    op[2] = fma(d2 * inv, lw[2], lb2[2]) * scale;
    op[3] = fma(d3 * inv, lw[3], lb2[3]) * scale;
  }
}

// ---------------- K1b: Vp = x @ WVP^T (fp64), layout [b][n][k][h] -----------------------------------
__global__ __launch_bounds__(256, 4) void k_proj_vp(
    const float* __restrict__ x, const double* __restrict__ WVP, double* __restrict__ Vp) {
  __shared__ __align__(16) double As[32][68];
  __shared__ __align__(16) double Bs[32][68];
  int rt = blockIdx.x, ot = blockIdx.y;
  int t = threadIdx.x, tr = t >> 4, tc = t & 15;

  double acc[4][4];
  #pragma unroll
  for (int i = 0; i < 4; i++)
    #pragma unroll
    for (int j = 0; j < 4; j++) acc[i][j] = 0.0;

  for (int k0 = 0; k0 < HID; k0 += 32) {
    #pragma unroll
    for (int i = 0; i < 8; i++) {
      int idx = t + i * 256;
      int r = idx >> 5, c = idx & 31;
      As[c][r] = (double)x[(size_t)(rt * 64 + r) * HID + k0 + c];
      Bs[c][r] = WVP[(size_t)(ot * 64 + r) * HID + k0 + c];
    }
    __syncthreads();
    #pragma unroll 2
    for (int kk = 0; kk < 32; kk++) {
      double2 a01 = *(const double2*)&As[kk][tr * 4];
      double2 a23 = *(const double2*)&As[kk][tr * 4 + 2];
      double2 b01 = *(const double2*)&Bs[kk][tc * 4];
      double2 b23 = *(const double2*)&Bs[kk][tc * 4 + 2];
      acc[0][0] = fma(a01.x, b01.x, acc[0][0]);
      acc[0][1] = fma(a01.x, b01.y, acc[0][1]);
      acc[0][2] = fma(a01.x, b23.x, acc[0][2]);
      acc[0][3] = fma(a01.x, b23.y, acc[0][3]);
      acc[1][0] = fma(a01.y, b01.x, acc[1][0]);
      acc[1][1] = fma(a01.y, b01.y, acc[1][1]);
      acc[1][2] = fma(a01.y, b23.x, acc[1][2]);
      acc[1][3] = fma(a01.y, b23.y, acc[1][3]);
      acc[2][0] = fma(a23.x, b01.x, acc[2][0]);
      acc[2][1] = fma(a23.x, b01.y, acc[2][1]);
      acc[2][2] = fma(a23.x, b23.x, acc[2][2]);
      acc[2][3] = fma(a23.x, b23.y, acc[2][3]);
      acc[3][0] = fma(a23.y, b01.x, acc[3][0]);
      acc[3][1] = fma(a23.y, b01.y, acc[3][1]);
      acc[3][2] = fma(a23.y, b23.x, acc[3][2]);
      acc[3][3] = fma(a23.y, b23.y, acc[3][3]);
    }
    __syncthreads();
  }
  #pragma unroll
  for (int i = 0; i < 4; i++) {
    int R = rt * 64 + tr * 4 + i;
    int b = R >> 11, k = R & 2047;
    int cc = ot * 64 + tc * 4;
    int n = cc >> 4, h = cc & 15;
    double* op = Vp + (((size_t)b * 16 + n) * SEQ + k) * 16 + h;
    op[0] = acc[i][0]; op[1] = acc[i][1]; op[2] = acc[i][2]; op[3] = acc[i][3];
  }
}

// ---------------- K2: attention, fp64, one query per thread, broadcast K/V reads --------------------
__global__ __launch_bounds__(256, 2) void k_attn(
    const double* __restrict__ Qh, const double* __restrict__ Kh,
    const double* __restrict__ Vp, double* __restrict__ pnum, double* __restrict__ pden) {
  int kh = blockIdx.x;  // key half
  int qt = blockIdx.y;  // query tile of 256
  int bn = blockIdx.z;  // b*16+n
  int t = threadIdx.x;
  int q = qt * 256 + t;

  __shared__ __align__(16) double2 K2[2048];   // 64 keys x 64 d (32 KB)
  __shared__ __align__(16) double2 V2[512];    // 64 keys x 16 h (8 KB)

  double2 qd2[32];
  const double2* qp2 = (const double2*)(Qh + ((size_t)bn * SEQ + q) * 64);
  #pragma unroll
  for (int i = 0; i < 32; i++) qd2[i] = qp2[i];

  double num[16];
  #pragma unroll
  for (int h = 0; h < 16; h++) num[h] = 0.0;
  double den = 0.0;

  int k0 = kh * 1024;
  for (int kc = 0; kc < 1024; kc += 64) {
    const double2* kb2 = (const double2*)(Kh + ((size_t)bn * SEQ + k0 + kc) * 64);
    #pragma unroll
    for (int i = 0; i < 8; i++) K2[t + i * 256] = kb2[t + i * 256];
    const double2* vb2 = (const double2*)(Vp + ((size_t)bn * SEQ + k0 + kc) * 16);
    #pragma unroll
    for (int i = 0; i < 2; i++) V2[t + i * 256] = vb2[t + i * 256];
    __syncthreads();
    #pragma unroll 1
    for (int kk = 0; kk < 64; kk += 4) {
      const double2* kr0 = K2 + kk * 32;
      const double2* kr1 = kr0 + 32;
      const double2* kr2 = kr0 + 64;
      const double2* kr3 = kr0 + 96;
      double s0 = 0.0, s1 = 0.0, s2 = 0.0, s3 = 0.0;
      #pragma unroll
      for (int i = 0; i < 32; i++) {
        double2 qv = qd2[i];
        double2 a0 = kr0[i];
        s0 = fma(qv.x, a0.x, s0); s0 = fma(qv.y, a0.y, s0);
        double2 a1 = kr1[i];
        s1 = fma(qv.x, a1.x, s1); s1 = fma(qv.y, a1.y, s1);
        double2 a2 = kr2[i];
        s2 = fma(qv.x, a2.x, s2); s2 = fma(qv.y, a2.y, s2);
        double2 a3 = kr3[i];
        s3 = fma(qv.x, a3.x, s3); s3 = fma(qv.y, a3.y, s3);
      }
      double e0 = fast_exp(s0);
      double e1 = fast_exp(s1);
      double e2 = fast_exp(s2);
      double e3 = fast_exp(s3);
      den += (e0 + e1) + (e2 + e3);
      const double2* vr0 = V2 + kk * 8;
      const double2* vr1 = vr0 + 8;
      const double2* vr2 = vr0 + 16;
      const double2* vr3 = vr0 + 24;
      #pragma unroll
      for (int j = 0; j < 8; j++) {
        double2 v0 = vr0[j], v1 = vr1[j], v2 = vr2[j], v3 = vr3[j];
        double a = num[2 * j], b = num[2 * j + 1];
        a = fma(e0, v0.x, a); b = fma(e0, v0.y, b);
        a = fma(e1, v1.x, a); b = fma(e1, v1.y, b);
        a = fma(e2, v2.x, a); b = fma(e2, v2.y, b);
        a = fma(e3, v3.x, a); b = fma(e3, v3.y, b);
        num[2 * j] = a; num[2 * j + 1] = b;
      }
    }
    __syncthreads();
  }
  size_t pb = ((size_t)kh * 32 + bn) * SEQ + q;
  pden[pb] = den;
  double2* pn2 = (double2*)(pnum + pb * 16);
  #pragma unroll
  for (int j = 0; j < 8; j++) {
    double2 w2; w2.x = num[2 * j]; w2.y = num[2 * j + 1];
    pn2[j] = w2;
  }
}

// ---------------- K2b: combine key-halves, divide, scatter into z-row layout (fp64) -----------------
__global__ void k_combine(const double* __restrict__ pnum, const double* __restrict__ pden,
                          double* __restrict__ zrow) {
  int id = blockIdx.x * 256 + threadIdx.x;  // bn*2048 + s
  int bn = id >> 11, s = id & 2047;
  int b = bn >> 4, n = bn & 15;
  double den = pden[id] + pden[65536 + id];
  int bp = b * 16 + (s >> 7);
  int np = ((s & 127) << 4) | n;
  size_t p0 = (size_t)id * 16, p1 = ((size_t)65536 + id) * 16;
  for (int h = 0; h < 16; h++) {
    double nm = pnum[p0 + h] + pnum[p1 + h];
    zrow[((size_t)bp * 16 + h) * 2048 + np] = nm / den;
  }
}

// ---------------- K3: exact top-128 per row via radix binary search on monotone uint64 keys ---------
__device__ inline unsigned long long dkey(double v) {
  unsigned long long u = (unsigned long long)__double_as_longlong(v);
  return (u & 0x8000000000000000ULL) ? ~u : (u | 0x8000000000000000ULL);
}

__global__ __launch_bounds__(256) void k_topk(const double* __restrict__ zrow,
                                              float* __restrict__ zs) {
  int row = blockIdx.x;
  int t = threadIdx.x;
  const double* src = zrow + (size_t)row * 2048;
  double v[8];
  unsigned long long key[8];
  #pragma unroll
  for (int i = 0; i < 8; i++) { v[i] = src[t + i * 256]; key[i] = dkey(v[i]); }

  __shared__ unsigned sh_cnt[4];
  __shared__ unsigned sh_cg[4], sh_ce[4];
  int w = t >> 6, lane = t & 63;

  unsigned long long lo = 0ULL, hi = 0xFFFFFFFFFFFFFFFFULL;
  while (lo < hi) {
    unsigned long long mid = lo + ((hi - lo) >> 1);
    unsigned c = 0;
    #pragma unroll
    for (int i = 0; i < 8; i++) c += (key[i] > mid) ? 1u : 0u;
    for (int off = 32; off; off >>= 1) c += __shfl_down(c, off);
    if (lane == 0) sh_cnt[w] = c;
    __syncthreads();
    unsigned total = sh_cnt[0] + sh_cnt[1] + sh_cnt[2] + sh_cnt[3];
    __syncthreads();
    if (total < TOPK) hi = mid; else lo = mid + 1;
  }
  unsigned long long tau = lo;

  unsigned cg = 0, ce = 0;
  #pragma unroll
  for (int i = 0; i < 8; i++) {
    cg += (key[i] > tau) ? 1u : 0u;
    ce += (key[i] == tau) ? 1u : 0u;
  }
  for (int off = 32; off; off >>= 1) { cg += __shfl_down(cg, off); ce += __shfl_down(ce, off); }
  if (lane == 0) { sh_cg[w] = cg; sh_ce[w] = ce; }
  __syncthreads();
  unsigned c_gt = sh_cg[0] + sh_cg[1] + sh_cg[2] + sh_cg[3];
  unsigned c_eq = sh_ce[0] + sh_ce[1] + sh_ce[2] + sh_ce[3];
  unsigned need = TOPK - c_gt;

  unsigned idxThr = 2048;
  if (c_eq > need) {
    unsigned l2 = 0, h2 = 2048;
    while (l2 < h2) {
      unsigned m2 = (l2 + h2) >> 1;
      unsigned c = 0;
      #pragma unroll
      for (int i = 0; i < 8; i++) {
        unsigned idx = (unsigned)(t + i * 256);
        c += (key[i] == tau && idx < m2) ? 1u : 0u;
      }
      for (int off = 32; off; off >>= 1) c += __shfl_down(c, off);
      if (lane == 0) sh_cnt[w] = c;
      __syncthreads();
      unsigned tot = sh_cnt[0] + sh_cnt[1] + sh_cnt[2] + sh_cnt[3];
      __syncthreads();
      if (tot >= need) h2 = m2; else l2 = m2 + 1;
    }
    idxThr = l2;
  }

  float* dst = zs + (size_t)row * 2048;
  #pragma unroll
  for (int i = 0; i < 8; i++) {
    unsigned idx = (unsigned)(t + i * 256);
    bool keep = (key[i] > tau) ||
                (key[i] == tau && (c_eq <= need || idx < idxThr));
    dst[idx] = keep ? (float)v[i] : 0.0f;
  }
}

// ---------------- K4: out = Z2 @ G  (4096 x 256 x 1024, fp32) ---------------------------------------
__global__ __launch_bounds__(256) void k_out(const float* __restrict__ zs,
                                             const float* __restrict__ G,
                                             float* __restrict__ out) {
  __shared__ float Al[64][65];
  __shared__ float Bl[64][65];
  int rt = blockIdx.x, ot = blockIdx.y;
  int t = threadIdx.x, tr = t >> 4, tc = t & 15;
  int Rb = rt * 64;
  int b = Rb >> 11, s0 = Rb & 2047;

  float acc[4][4];
  #pragma unroll
  for (int i = 0; i < 4; i++)
    #pragma unroll
    for (int j = 0; j < 4; j++) acc[i][j] = 0.0f;

  for (int kc = 0; kc < 256; kc += 64) {
    #pragma unroll
    for (int i = 0; i < 16; i++) {
      int idx = t + i * 256;
      int c = idx >> 6, r = idx & 63;
      int cc = kc + c;
      Al[r][c] = zs[(((size_t)(b * 16 + (cc >> 4))) * 16 + (cc & 15)) * 2048 + s0 + r];
      Bl[c][r] = G[(size_t)(kc + c) * HID + ot * 64 + r];
    }
    __syncthreads();
    #pragma unroll 1
    for (int kk = 0; kk < 64; kk++) {
      float a[4], bb[4];
      #pragma unroll
      for (int i = 0; i < 4; i++) a[i] = Al[tr * 4 + i][kk];
      #pragma unroll
      for (int j = 0; j < 4; j++) bb[j] = Bl[kk][tc * 4 + j];
      #pragma unroll
      for (int i = 0; i < 4; i++)
        #pragma unroll
        for (int j = 0; j < 4; j++) acc[i][j] = fmaf(a[i], bb[j], acc[i][j]);
    }
    __syncthreads();
  }
  #pragma unroll
  for (int i = 0; i < 4; i++) {
    int R = Rb + tr * 4 + i;
    #pragma unroll
    for (int j = 0; j < 4; j++)
      out[(size_t)R * HID + ot * 64 + tc * 4 + j] = acc[i][j];
  }
}

// ---------------- launch ----------------------------------------------------------------------------
extern "C" void kernel_launch(void* const* d_in, const int* in_sizes, int n_in,
                              void* d_out, int out_size, void* d_ws, size_t ws_size,
                              hipStream_t stream) {
  const float* x   = (const float*)d_in[0];
  const float* W_Q = (const float*)d_in[1];
  const float* W_K = (const float*)d_in[2];
  const float* W_V = (const float*)d_in[3];
  const float* W_O = (const float*)d_in[4];
  const float* qw  = (const float*)d_in[5];
  const float* qb  = (const float*)d_in[6];
  const float* kw  = (const float*)d_in[7];
  const float* kb  = (const float*)d_in[8];
  const float* sWV = (const float*)d_in[9];
  const float* sWO = (const float*)d_in[10];
  float* out = (float*)d_out;
  char* ws = (char*)d_ws;

  double* Qh   = (double*)(ws + 0);
  double* Kh   = (double*)(ws + 33554432ULL);
  double* Vp   = (double*)(ws + 67108864ULL);
  double* WVP  = (double*)(ws + 75497472ULL);
  float*  G    = (float*) (ws + 77594624ULL);
  double* vw   = (double*)(ws + 78643200ULL);
  double* ow   = (double*)(ws + 78651392ULL);
  double* pnum = (double*)(ws + 78659584ULL);
  double* pden = (double*)(ws + 95436800ULL);
  double* zrow = (double*)(ws + 0);
  float*  zs   = (float*) (ws + 8388608ULL);

  k_prep_means<<<dim3(1), dim3(256), 0, stream>>>(sWV, sWO, vw, ow);
  k_prep_wvp_g<<<dim3(512), dim3(256), 0, stream>>>(W_V, W_O, vw, ow, WVP, G);
  k_proj_qk<<<dim3(64, 32), dim3(256), 0, stream>>>(x, W_Q, W_K, qw, qb, kw, kb, Qh, Kh);
  k_proj_vp<<<dim3(64, 4), dim3(256), 0, stream>>>(x, WVP, Vp);
  k_attn<<<dim3(2, 8, 32), dim3(256), 0, stream>>>(Qh, Kh, Vp, pnum, pden);
  k_combine<<<dim3(256), dim3(256), 0, stream>>>(pnum, pden, zrow);
  k_topk<<<dim3(512), dim3(256), 0, stream>>>(zrow, zs);
  k_out<<<dim3(64, 16), dim3(256), 0, stream>>>(zs, G, out);
}

// Round 4
// 1687.933 us; speedup vs baseline: 1.1759x; 1.1759x over previous
//
#include <hip/hip_runtime.h>
#include <math.h>

#define NB   2
#define SEQ  2048
#define NHD  16
#define HDD  64
#define HID  1024
#define TOPK 128

// ---------------- fast fp64 exp(s): branchless, rel err ~7e-12 --------------------------------------
__device__ inline double fast_exp(double s) {
  const double LOG2E = 1.4426950408889634073599246810019;
  double t = s * LOG2E;
  double n = __builtin_rint(t);
  double f = t - n;                                   // |f| <= 0.5
  double r = f * 0.69314718055994530941723212145818;  // ln2
  double p = 2.7557319223985890652557319223986e-6;    // 1/9!
  p = fma(p, r, 2.4801587301587301587301587301587e-5);
  p = fma(p, r, 1.9841269841269841269841269841270e-4);
  p = fma(p, r, 1.3888888888888888888888888888889e-3);
  p = fma(p, r, 8.3333333333333333333333333333333e-3);
  p = fma(p, r, 4.1666666666666666666666666666667e-2);
  p = fma(p, r, 1.6666666666666666666666666666667e-1);
  p = fma(p, r, 0.5);
  p = fma(p, r, 1.0);
  p = fma(p, r, 1.0);
  int ni = (int)n;
  double sc = __longlong_as_double((long long)(1023 + ni) << 52);
  return p * sc;
}

// ---------------- pair butterfly: x + partner(x) across lane^1, via DPP quad_perm (VALU pipe) -------
__device__ inline double pair_sum(double x) {
#if defined(__has_builtin) && __has_builtin(__builtin_amdgcn_update_dpp)
  // quad_perm [1,0,3,2] = xor1 within each quad: ctrl = 1|(0<<2)|(3<<4)|(2<<6) = 0xB1
  int lo = __builtin_amdgcn_update_dpp(0, __double2loint(x), 0xB1, 0xF, 0xF, true);
  int hi = __builtin_amdgcn_update_dpp(0, __double2hiint(x), 0xB1, 0xF, 0xF, true);
  return x + __hiloint2double(hi, lo);
#else
  return x + __shfl_xor(x, 1, 64);
#endif
}

// ---------------- K0a: vw = mean(sparse_W_V, axis=2), ow = mean(sparse_W_O, axis=1) (fp64) ----------
__global__ void k_prep_means(const float* __restrict__ sWV, const float* __restrict__ sWO,
                             double* __restrict__ vw, double* __restrict__ ow) {
  int t = threadIdx.x;
  for (int o = t; o < NHD * HDD; o += 256) {
    const float* p = sWV + (size_t)o * TOPK;
    double s = 0.0;
    for (int i = 0; i < TOPK; i++) s += (double)p[i];
    vw[o] = s * (1.0 / 128.0);
    int h = o >> 6, d = o & 63;
    const float* q = sWO + ((size_t)h * TOPK) * HDD + d;
    double s2 = 0.0;
    for (int i = 0; i < TOPK; i++) s2 += (double)q[(size_t)i * HDD];
    ow[o] = s2 * (1.0 / 128.0);
  }
}

// ---------------- K0b: WVP / G precompute -----------------------------------------------------------
__global__ void k_prep_wvp_g(const float* __restrict__ W_V, const float* __restrict__ W_O,
                             const double* __restrict__ vw, const double* __restrict__ ow,
                             double* __restrict__ WVP, float* __restrict__ G) {
  int blk = blockIdx.x;
  int t = threadIdx.x;
  if (blk < 256) {
    int n = blk >> 4, h = blk & 15;
    for (int j = t; j < HID; j += 256) {
      double s = 0.0;
      for (int d = 0; d < 64; d++)
        s += (double)W_V[(size_t)(n * 64 + d) * HID + j] * vw[h * 64 + d];
      WVP[(size_t)blk * HID + j] = s;
    }
  } else {
    int r = blk - 256;
    int m = r >> 4, h = r & 15;
    for (int o = t; o < HID; o += 256) {
      double s = 0.0;
      for (int d = 0; d < 64; d++)
        s += ow[h * 64 + d] * (double)W_O[(size_t)o * HID + m * 64 + d];
      G[(size_t)r * HID + o] = (float)s;
    }
  }
}

// ---------------- K1: Q/K projection (fp64) + per-head LayerNorm via shfl, store fp64 ---------------
// Q is pre-scaled by 0.125 (exact power-of-two; scores become softmax-ready).
__global__ __launch_bounds__(256, 4) void k_proj_qk(
    const float* __restrict__ x, const float* __restrict__ W_Q, const float* __restrict__ W_K,
    const float* __restrict__ qw, const float* __restrict__ qb,
    const float* __restrict__ kw, const float* __restrict__ kb,
    double* __restrict__ Qh, double* __restrict__ Kh) {
  __shared__ __align__(16) double As[32][68];  // [k][row]
  __shared__ __align__(16) double Bs[32][68];

  int rt = blockIdx.x, ot = blockIdx.y;
  bool isQ = (ot < 16);
  const float* W = isQ ? W_Q : W_K;
  int head = isQ ? ot : ot - 16;
  int t = threadIdx.x;
  int tr = t >> 4, tc = t & 15;

  double acc[4][4];
  #pragma unroll
  for (int i = 0; i < 4; i++)
    #pragma unroll
    for (int j = 0; j < 4; j++) acc[i][j] = 0.0;

  for (int k0 = 0; k0 < HID; k0 += 32) {
    #pragma unroll
    for (int i = 0; i < 8; i++) {
      int idx = t + i * 256;
      int r = idx >> 5, c = idx & 31;
      As[c][r] = (double)x[(size_t)(rt * 64 + r) * HID + k0 + c];
      Bs[c][r] = (double)W[(size_t)(head * 64 + r) * HID + k0 + c];
    }
    __syncthreads();
    #pragma unroll 2
    for (int kk = 0; kk < 32; kk++) {
      double2 a01 = *(const double2*)&As[kk][tr * 4];
      double2 a23 = *(const double2*)&As[kk][tr * 4 + 2];
      double2 b01 = *(const double2*)&Bs[kk][tc * 4];
      double2 b23 = *(const double2*)&Bs[kk][tc * 4 + 2];
      acc[0][0] = fma(a01.x, b01.x, acc[0][0]);
      acc[0][1] = fma(a01.x, b01.y, acc[0][1]);
      acc[0][2] = fma(a01.x, b23.x, acc[0][2]);
      acc[0][3] = fma(a01.x, b23.y, acc[0][3]);
      acc[1][0] = fma(a01.y, b01.x, acc[1][0]);
      acc[1][1] = fma(a01.y, b01.y, acc[1][1]);
      acc[1][2] = fma(a01.y, b23.x, acc[1][2]);
      acc[1][3] = fma(a01.y, b23.y, acc[1][3]);
      acc[2][0] = fma(a23.x, b01.x, acc[2][0]);
      acc[2][1] = fma(a23.x, b01.y, acc[2][1]);
      acc[2][2] = fma(a23.x, b23.x, acc[2][2]);
      acc[2][3] = fma(a23.x, b23.y, acc[2][3]);
      acc[3][0] = fma(a23.y, b01.x, acc[3][0]);
      acc[3][1] = fma(a23.y, b01.y, acc[3][1]);
      acc[3][2] = fma(a23.y, b23.x, acc[3][2]);
      acc[3][3] = fma(a23.y, b23.y, acc[3][3]);
    }
    __syncthreads();
  }

  double lw[4], lb2[4];
  {
    const float* lwp = isQ ? qw : kw;
    const float* lbp = isQ ? qb : kb;
    #pragma unroll
    for (int j = 0; j < 4; j++) {
      lw[j]  = (double)lwp[tc * 4 + j];
      lb2[j] = (double)lbp[tc * 4 + j];
    }
  }
  double* outp = isQ ? Qh : Kh;
  double scale = isQ ? 0.125 : 1.0;  // exact
  #pragma unroll
  for (int i = 0; i < 4; i++) {
    double s = (acc[i][0] + acc[i][1]) + (acc[i][2] + acc[i][3]);
    s += __shfl_xor(s, 1); s += __shfl_xor(s, 2);
    s += __shfl_xor(s, 4); s += __shfl_xor(s, 8);
    double mu = s * (1.0 / 64.0);
    double d0 = acc[i][0] - mu, d1 = acc[i][1] - mu;
    double d2 = acc[i][2] - mu, d3 = acc[i][3] - mu;
    double v = (d0 * d0 + d1 * d1) + (d2 * d2 + d3 * d3);
    v += __shfl_xor(v, 1); v += __shfl_xor(v, 2);
    v += __shfl_xor(v, 4); v += __shfl_xor(v, 8);
    double inv = 1.0 / sqrt(v * (1.0 / 64.0) + 1e-5);
    int R = rt * 64 + tr * 4 + i;
    int b = R >> 11, ss = R & 2047;
    double* op = outp + (((size_t)b * 16 + head) * SEQ + ss) * 64 + tc * 4;
    op[0] = fma(d0 * inv, lw[0], lb2[0]) * scale;
    op[1] = fma(d1 * inv, lw[1], lb2[1]) * scale;
    op[2] = fma(d2 * inv, lw[2], lb2[2]) * scale;
    op[3] = fma(d3 * inv, lw[3], lb2[3]) * scale;
  }
}

// ---------------- K1b: Vp = x @ WVP^T (fp64), layout [b][n][k][h] -----------------------------------
__global__ __launch_bounds__(256, 4) void k_proj_vp(
    const float* __restrict__ x, const double* __restrict__ WVP, double* __restrict__ Vp) {
  __shared__ __align__(16) double As[32][68];
  __shared__ __align__(16) double Bs[32][68];
  int rt = blockIdx.x, ot = blockIdx.y;
  int t = threadIdx.x, tr = t >> 4, tc = t & 15;

  double acc[4][4];
  #pragma unroll
  for (int i = 0; i < 4; i++)
    #pragma unroll
    for (int j = 0; j < 4; j++) acc[i][j] = 0.0;

  for (int k0 = 0; k0 < HID; k0 += 32) {
    #pragma unroll
    for (int i = 0; i < 8; i++) {
      int idx = t + i * 256;
      int r = idx >> 5, c = idx & 31;
      As[c][r] = (double)x[(size_t)(rt * 64 + r) * HID + k0 + c];
      Bs[c][r] = WVP[(size_t)(ot * 64 + r) * HID + k0 + c];
    }
    __syncthreads();
    #pragma unroll 2
    for (int kk = 0; kk < 32; kk++) {
      double2 a01 = *(const double2*)&As[kk][tr * 4];
      double2 a23 = *(const double2*)&As[kk][tr * 4 + 2];
      double2 b01 = *(const double2*)&Bs[kk][tc * 4];
      double2 b23 = *(const double2*)&Bs[kk][tc * 4 + 2];
      acc[0][0] = fma(a01.x, b01.x, acc[0][0]);
      acc[0][1] = fma(a01.x, b01.y, acc[0][1]);
      acc[0][2] = fma(a01.x, b23.x, acc[0][2]);
      acc[0][3] = fma(a01.x, b23.y, acc[0][3]);
      acc[1][0] = fma(a01.y, b01.x, acc[1][0]);
      acc[1][1] = fma(a01.y, b01.y, acc[1][1]);
      acc[1][2] = fma(a01.y, b23.x, acc[1][2]);
      acc[1][3] = fma(a01.y, b23.y, acc[1][3]);
      acc[2][0] = fma(a23.x, b01.x, acc[2][0]);
      acc[2][1] = fma(a23.x, b01.y, acc[2][1]);
      acc[2][2] = fma(a23.x, b23.x, acc[2][2]);
      acc[2][3] = fma(a23.x, b23.y, acc[2][3]);
      acc[3][0] = fma(a23.y, b01.x, acc[3][0]);
      acc[3][1] = fma(a23.y, b01.y, acc[3][1]);
      acc[3][2] = fma(a23.y, b23.x, acc[3][2]);
      acc[3][3] = fma(a23.y, b23.y, acc[3][3]);
    }
    __syncthreads();
  }
  #pragma unroll
  for (int i = 0; i < 4; i++) {
    int R = rt * 64 + tr * 4 + i;
    int b = R >> 11, k = R & 2047;
    int cc = ot * 64 + tc * 4;
    int n = cc >> 4, h = cc & 15;
    double* op = Vp + (((size_t)b * 16 + n) * SEQ + k) * 16 + h;
    op[0] = acc[i][0]; op[1] = acc[i][1]; op[2] = acc[i][2]; op[3] = acc[i][3];
  }
}

// ---------------- Kz: zero pnum/pden (harness poisons ws; atomics need zeros) -----------------------
__global__ void k_zero(double* __restrict__ p) {
  size_t i = ((size_t)blockIdx.x * 256 + threadIdx.x) * 2;
  double2 z; z.x = 0.0; z.y = 0.0;
  ((double2*)p)[(size_t)blockIdx.x * 256 + threadIdx.x] = z;
  (void)i;
}

// ---------------- K2: attention, fp64, pair-per-query d-split, bank-safe LDS, DPP butterfly ---------
// grid (kh=4, qt=16, bn=32) = 2048 blocks; 4 waves/SIMD; atomic fp64 combine into pnum/pden.
__global__ __launch_bounds__(256, 4) void k_attn(
    const double* __restrict__ Qh, const double* __restrict__ Kh,
    const double* __restrict__ Vp, double* __restrict__ pnum, double* __restrict__ pden) {
  int kh = blockIdx.x;  // key quarter (512 keys)
  int qt = blockIdx.y;  // query tile of 128
  int bn = blockIdx.z;  // b*16+n
  int t = threadIdx.x;
  int q = qt * 128 + (t >> 1);
  int p = t & 1;

  // K: 32 keys x (2 halves x 34 doubles) = 2176 doubles (17408 B); halves 4 banks apart
  // V: 32 keys x 18 doubles = 576 doubles (4608 B); rows 4 banks apart
  __shared__ __align__(16) double Kl[32 * 68];
  __shared__ __align__(16) double Vl[32 * 18];

  double2 qd2[16];
  const double2* qp2 = (const double2*)(Qh + ((size_t)bn * SEQ + q) * 64 + p * 32);
  #pragma unroll
  for (int i = 0; i < 16; i++) qd2[i] = qp2[i];

  double num[16];
  #pragma unroll
  for (int h = 0; h < 16; h++) num[h] = 0.0;
  double den = 0.0;

  int k0 = kh * 512;
  int kt = t >> 3;              // staging: key 0..31
  int d0 = (t & 7) * 8;         // staging: 8 consecutive d
  int h0 = (t & 7) * 2;         // staging: 2 consecutive h
  for (int kc = 0; kc < 512; kc += 32) {
    // stage K chunk (coalesced global, half-padded LDS)
    {
      const double2* src = (const double2*)(Kh + ((size_t)bn * SEQ + k0 + kc + kt) * 64 + d0);
      double2* dst = (double2*)(Kl + kt * 68 + d0 + (d0 >= 32 ? 2 : 0));
      #pragma unroll
      for (int j = 0; j < 4; j++) dst[j] = src[j];
    }
    // stage V chunk
    {
      const double2* src = (const double2*)(Vp + ((size_t)bn * SEQ + k0 + kc + kt) * 16 + h0);
      *(double2*)(Vl + kt * 18 + h0) = src[0];
    }
    __syncthreads();
    #pragma unroll 1
    for (int kk = 0; kk < 32; kk += 2) {
      const double2* kr0 = (const double2*)Kl + kk * 34 + p * 17;
      const double2* kr1 = kr0 + 34;
      double s0 = 0.0, s1 = 0.0;
      #pragma unroll
      for (int i = 0; i < 16; i++) {
        double2 qv = qd2[i];
        double2 a0 = kr0[i];
        s0 = fma(qv.x, a0.x, s0); s0 = fma(qv.y, a0.y, s0);
        double2 a1 = kr1[i];
        s1 = fma(qv.x, a1.x, s1); s1 = fma(qv.y, a1.y, s1);
      }
      s0 = pair_sum(s0);            // full dot for key kk
      s1 = pair_sum(s1);            // full dot for key kk+1
      double sv = p ? s1 : s0;      // this lane's designated key
      double e = fast_exp(sv);
      den += e;
      const double2* vr = (const double2*)(Vl + (kk + p) * 18);
      #pragma unroll
      for (int j = 0; j < 8; j++) {
        double2 v = vr[j];
        num[2 * j]     = fma(e, v.x, num[2 * j]);
        num[2 * j + 1] = fma(e, v.y, num[2 * j + 1]);
      }
    }
    __syncthreads();
  }

  // pair combine (once), then device-scope fp64 atomics into the global accumulators
  den = pair_sum(den);
  #pragma unroll
  for (int h = 0; h < 16; h++) num[h] = pair_sum(num[h]);
  if (p == 0) {
    double* dst = pnum + ((size_t)bn * SEQ + q) * 16;
    #pragma unroll
    for (int h = 0; h < 16; h++) atomicAdd(dst + h, num[h]);
    atomicAdd(pden + (size_t)bn * SEQ + q, den);
  }
}

// ---------------- K2b: divide, scatter into z-row layout (fp64) -------------------------------------
__global__ void k_combine(const double* __restrict__ pnum, const double* __restrict__ pden,
                          double* __restrict__ zrow) {
  int id = blockIdx.x * 256 + threadIdx.x;  // bn*2048 + s
  int bn = id >> 11, s = id & 2047;
  int b = bn >> 4, n = bn & 15;
  double den = pden[id];
  int bp = b * 16 + (s >> 7);
  int np = ((s & 127) << 4) | n;
  const double* pn = pnum + (size_t)id * 16;
  for (int h = 0; h < 16; h++) {
    zrow[((size_t)bp * 16 + h) * 2048 + np] = pn[h] / den;
  }
}

// ---------------- K3: exact top-128 per row via radix binary search on monotone uint64 keys ---------
__device__ inline unsigned long long dkey(double v) {
  unsigned long long u = (unsigned long long)__double_as_longlong(v);
  return (u & 0x8000000000000000ULL) ? ~u : (u | 0x8000000000000000ULL);
}

__global__ __launch_bounds__(256) void k_topk(const double* __restrict__ zrow,
                                              float* __restrict__ zs) {
  int row = blockIdx.x;
  int t = threadIdx.x;
  const double* src = zrow + (size_t)row * 2048;
  double v[8];
  unsigned long long key[8];
  #pragma unroll
  for (int i = 0; i < 8; i++) { v[i] = src[t + i * 256]; key[i] = dkey(v[i]); }

  __shared__ unsigned sh_cnt[4];
  __shared__ unsigned sh_cg[4], sh_ce[4];
  int w = t >> 6, lane = t & 63;

  unsigned long long lo = 0ULL, hi = 0xFFFFFFFFFFFFFFFFULL;
  while (lo < hi) {
    unsigned long long mid = lo + ((hi - lo) >> 1);
    unsigned c = 0;
    #pragma unroll
    for (int i = 0; i < 8; i++) c += (key[i] > mid) ? 1u : 0u;
    for (int off = 32; off; off >>= 1) c += __shfl_down(c, off);
    if (lane == 0) sh_cnt[w] = c;
    __syncthreads();
    unsigned total = sh_cnt[0] + sh_cnt[1] + sh_cnt[2] + sh_cnt[3];
    __syncthreads();
    if (total < TOPK) hi = mid; else lo = mid + 1;
  }
  unsigned long long tau = lo;

  unsigned cg = 0, ce = 0;
  #pragma unroll
  for (int i = 0; i < 8; i++) {
    cg += (key[i] > tau) ? 1u : 0u;
    ce += (key[i] == tau) ? 1u : 0u;
  }
  for (int off = 32; off; off >>= 1) { cg += __shfl_down(cg, off); ce += __shfl_down(ce, off); }
  if (lane == 0) { sh_cg[w] = cg; sh_ce[w] = ce; }
  __syncthreads();
  unsigned c_gt = sh_cg[0] + sh_cg[1] + sh_cg[2] + sh_cg[3];
  unsigned c_eq = sh_ce[0] + sh_ce[1] + sh_ce[2] + sh_ce[3];
  unsigned need = TOPK - c_gt;

  unsigned idxThr = 2048;
  if (c_eq > need) {
    unsigned l2 = 0, h2 = 2048;
    while (l2 < h2) {
      unsigned m2 = (l2 + h2) >> 1;
      unsigned c = 0;
      #pragma unroll
      for (int i = 0; i < 8; i++) {
        unsigned idx = (unsigned)(t + i * 256);
        c += (key[i] == tau && idx < m2) ? 1u : 0u;
      }
      for (int off = 32; off; off >>= 1) c += __shfl_down(c, off);
      if (lane == 0) sh_cnt[w] = c;
      __syncthreads();
      unsigned tot = sh_cnt[0] + sh_cnt[1] + sh_cnt[2] + sh_cnt[3];
      __syncthreads();
      if (tot >= need) h2 = m2; else l2 = m2 + 1;
    }
    idxThr = l2;
  }

  float* dst = zs + (size_t)row * 2048;
  #pragma unroll
  for (int i = 0; i < 8; i++) {
    unsigned idx = (unsigned)(t + i * 256);
    bool keep = (key[i] > tau) ||
                (key[i] == tau && (c_eq <= need || idx < idxThr));
    dst[idx] = keep ? (float)v[i] : 0.0f;
  }
}

// ---------------- K4: out = Z2 @ G  (4096 x 256 x 1024, fp32) ---------------------------------------
__global__ __launch_bounds__(256) void k_out(const float* __restrict__ zs,
                                             const float* __restrict__ G,
                                             float* __restrict__ out) {
  __shared__ float Al[64][65];
  __shared__ float Bl[64][65];
  int rt = blockIdx.x, ot = blockIdx.y;
  int t = threadIdx.x, tr = t >> 4, tc = t & 15;
  int Rb = rt * 64;
  int b = Rb >> 11, s0 = Rb & 2047;

  float acc[4][4];
  #pragma unroll
  for (int i = 0; i < 4; i++)
    #pragma unroll
    for (int j = 0; j < 4; j++) acc[i][j] = 0.0f;

  for (int kc = 0; kc < 256; kc += 64) {
    #pragma unroll
    for (int i = 0; i < 16; i++) {
      int idx = t + i * 256;
      int c = idx >> 6, r = idx & 63;
      int cc = kc + c;
      Al[r][c] = zs[(((size_t)(b * 16 + (cc >> 4))) * 16 + (cc & 15)) * 2048 + s0 + r];
      Bl[c][r] = G[(size_t)(kc + c) * HID + ot * 64 + r];
    }
    __syncthreads();
    #pragma unroll 1
    for (int kk = 0; kk < 64; kk++) {
      float a[4], bb[4];
      #pragma unroll
      for (int i = 0; i < 4; i++) a[i] = Al[tr * 4 + i][kk];
      #pragma unroll
      for (int j = 0; j < 4; j++) bb[j] = Bl[kk][tc * 4 + j];
      #pragma unroll
      for (int i = 0; i < 4; i++)
        #pragma unroll
        for (int j = 0; j < 4; j++) acc[i][j] = fmaf(a[i], bb[j], acc[i][j]);
    }
    __syncthreads();
  }
  #pragma unroll
  for (int i = 0; i < 4; i++) {
    int R = Rb + tr * 4 + i;
    #pragma unroll
    for (int j = 0; j < 4; j++)
      out[(size_t)R * HID + ot * 64 + tc * 4 + j] = acc[i][j];
  }
}

// ---------------- launch ----------------------------------------------------------------------------
extern "C" void kernel_launch(void* const* d_in, const int* in_sizes, int n_in,
                              void* d_out, int out_size, void* d_ws, size_t ws_size,
                              hipStream_t stream) {
  const float* x   = (const float*)d_in[0];
  const float* W_Q = (const float*)d_in[1];
  const float* W_K = (const float*)d_in[2];
  const float* W_V = (const float*)d_in[3];
  const float* W_O = (const float*)d_in[4];
  const float* qw  = (const float*)d_in[5];
  const float* qb  = (const float*)d_in[6];
  const float* kw  = (const float*)d_in[7];
  const float* kb  = (const float*)d_in[8];
  const float* sWV = (const float*)d_in[9];
  const float* sWO = (const float*)d_in[10];
  float* out = (float*)d_out;
  char* ws = (char*)d_ws;

  double* Qh   = (double*)(ws + 0);           // 33,554,432
  double* Kh   = (double*)(ws + 33554432ULL); // 33,554,432
  double* Vp   = (double*)(ws + 67108864ULL); // 8,388,608
  double* WVP  = (double*)(ws + 75497472ULL); // 2,097,152
  float*  G    = (float*) (ws + 77594624ULL); // 1,048,576
  double* vw   = (double*)(ws + 78643200ULL); // 8,192
  double* ow   = (double*)(ws + 78651392ULL); // 8,192
  double* pnum = (double*)(ws + 78659584ULL); // 8,388,608
  double* pden = (double*)(ws + 87048192ULL); // 524,288 -> end 87,572,480 (within proven 96.5 MB)
  double* zrow = (double*)(ws + 0);           // overlay on Qh (dead after k_attn)
  float*  zs   = (float*) (ws + 8388608ULL);  // overlay

  k_prep_means<<<dim3(1), dim3(256), 0, stream>>>(sWV, sWO, vw, ow);
  k_prep_wvp_g<<<dim3(512), dim3(256), 0, stream>>>(W_V, W_O, vw, ow, WVP, G);
  k_proj_qk<<<dim3(64, 32), dim3(256), 0, stream>>>(x, W_Q, W_K, qw, qb, kw, kb, Qh, Kh);
  k_proj_vp<<<dim3(64, 4), dim3(256), 0, stream>>>(x, WVP, Vp);
  // zero pnum+pden: 8,912,896 B = 557,056 double2 = 2176 blocks x 256 threads
  k_zero<<<dim3(2176), dim3(256), 0, stream>>>(pnum);
  k_attn<<<dim3(4, 16, 32), dim3(256), 0, stream>>>(Qh, Kh, Vp, pnum, pden);
  k_combine<<<dim3(256), dim3(256), 0, stream>>>(pnum, pden, zrow);
  k_topk<<<dim3(512), dim3(256), 0, stream>>>(zrow, zs);
  k_out<<<dim3(64, 16), dim3(256), 0, stream>>>(zs, G, out);
}